// Round 9
// baseline (272.486 us; speedup 1.0000x reference)
//
#include <hip/hip_runtime.h>
#include <math.h>

#define BATCH 2048
#define LDIM 64
#define EDIM 256
#define UDIM 512

typedef __attribute__((ext_vector_type(8))) _Float16 half8;
typedef __attribute__((ext_vector_type(4))) _Float16 half4;
typedef __attribute__((ext_vector_type(4))) float floatx4;

__device__ inline float tanh_fast(float x) {
    float t = __builtin_amdgcn_exp2f(x * 2.88539008177792681f);
    return 1.f - 2.f * __builtin_amdgcn_rcpf(t + 1.f);
}
__device__ inline half8 cvt8(float4 f0, float4 f1) {
    half8 h;
    h[0] = (_Float16)f0.x; h[1] = (_Float16)f0.y;
    h[2] = (_Float16)f0.z; h[3] = (_Float16)f0.w;
    h[4] = (_Float16)f1.x; h[5] = (_Float16)f1.y;
    h[6] = (_Float16)f1.z; h[7] = (_Float16)f1.w;
    return h;
}
__device__ inline half4 cvt4(float4 f) {
    half4 h;
    h[0] = (_Float16)f.x; h[1] = (_Float16)f.y;
    h[2] = (_Float16)f.z; h[3] = (_Float16)f.w;
    return h;
}
// B-fragment pointer: layout [kc][ntg(32)][lane(64)][8 fp16]
__device__ inline const half8* bfrag(const unsigned short* F, int kc, int ntg, int l) {
    return (const half8*)(F + ((((size_t)kc * 32 + ntg) * 64 + l) << 3));
}

// ---- prep_all: ONE kernel, no internal dependencies.
//   blocks 0..15   : W1 fp32 -> F1 fp16 B-fragments (2 units of the old
//                    256-thread prep_frag job per 512-thread block).
//   blocks 16..143 : ph[r0..r0+16) = hidden @ W2 + b1 + b2 via fp16 MFMA,
//                    W2 staged raw (fp32) per-kc into LDS, fragments built
//                    inline (same (_Float16)W2[k][n] values as old F2 path
//                    -> bit-identical ph).
__global__ __launch_bounds__(512) void prep_all(
    const float* __restrict__ W1, const float* __restrict__ W2,
    const float* __restrict__ hidden,
    const float* __restrict__ b1, const float* __restrict__ b2,
    unsigned short* __restrict__ F1, float* __restrict__ ph)
{
    __shared__ float S[32 * 512];   // 64 KB: ph view [32][512]; F1 view 2x[32][128]
    const int tid = threadIdx.x;
    const int bid = blockIdx.x;

    if (bid < 16) {
        // ---- F1 fragment prep: unit u = bid*2 + half, half = tid>>8 ----
        const int half = tid >> 8;
        const int t    = tid & 255;
        const int u    = bid * 2 + half;           // 0..31
        const int kc   = u >> 2, grp = u & 3;      // kc 0..7, grp 0..3
        float* Sh = S + half * (32 * 128);
        const float* src = W1 + (size_t)kc * 32 * UDIM + grp * 128;
        float4* Sv = (float4*)Sh;
#pragma unroll
        for (int i = 0; i < 4; ++i) {
            int f = t + i * 256;
            int k = f >> 5, c4 = f & 31;
            Sv[f] = *(const float4*)(src + (size_t)k * UDIM + c4 * 4);
        }
        __syncthreads();
#pragma unroll
        for (int i = 0; i < 2; ++i) {
            int uu = t + i * 256;
            int lane = uu & 63, ntl = uu >> 6;
            int n_loc = ntl * 16 + (lane & 15);
            int k0 = (lane >> 4) * 8;
            half8 h;
#pragma unroll
            for (int j = 0; j < 8; ++j)
                h[j] = (_Float16)Sh[(k0 + j) * 128 + n_loc];
            int ntg = grp * 8 + ntl;
            *(half8*)(F1 + (((size_t)kc * 32 + ntg) * 64 + lane) * 8) = h;
        }
        return;
    }

    // ---- ph block: rows [r0, r0+16) ----
    const int bp = bid - 16;           // 0..127
    const int r0 = bp * 16;
    const int w = tid >> 6;            // 0..7
    const int l = tid & 63;
    const int k0 = (l >> 4) * 8;

    floatx4 acc[4];
#pragma unroll
    for (int i = 0; i < 4; ++i) acc[i] = (floatx4){0.f, 0.f, 0.f, 0.f};

    const float* ap = hidden + (size_t)(r0 + (l & 15)) * UDIM + ((l >> 4) << 3);

    for (int kc = 0; kc < 16; ++kc) {
        // stage W2 slab rows [kc*32, kc*32+32) x 512 cols (64 KB), coalesced
#pragma unroll
        for (int i = 0; i < 8; ++i) {
            int unit = tid + 512 * i;          // 0..4095 float4 units
            int row = unit >> 7, c4 = unit & 127;
            *(float4*)&S[row * 512 + c4 * 4] =
                *(const float4*)(W2 + ((size_t)(kc * 32 + row)) * UDIM + c4 * 4);
        }
        __syncthreads();

        // A fragment (identical to old prep_ph)
        float4 a0 = *(const float4*)(ap + kc * 32);
        float4 a1 = *(const float4*)(ap + kc * 32 + 4);
        half8 a = cvt8(a0, a1);

#pragma unroll
        for (int nt = 0; nt < 4; ++nt) {
            const int ncol = (w * 4 + nt) * 16 + (l & 15);
            half8 bf;
#pragma unroll
            for (int j = 0; j < 8; ++j)
                bf[j] = (_Float16)S[(k0 + j) * 512 + ncol];
            acc[nt] = __builtin_amdgcn_mfma_f32_16x16x32_f16(a, bf, acc[nt], 0, 0, 0);
        }
        __syncthreads();   // slab consumed; safe to overwrite next kc
    }

#pragma unroll
    for (int nt = 0; nt < 4; ++nt) {
        const int n = (w * 4 + nt) * 16 + (l & 15);
        const float bias = b1[n] + b2[n];
#pragma unroll
        for (int r = 0; r < 4; ++r) {
            const int m = (l >> 4) * 4 + r;
            ph[(size_t)(r0 + m) * UDIM + n] = acc[nt][r] + bias;
        }
    }
}

// ---- main: UNCHANGED from round 8 (93.8 us, clean counters). ----
__global__ __launch_bounds__(512, 4) void attn_main(
    const float* __restrict__ feat, const unsigned short* __restrict__ F1,
    const float* __restrict__ ph, const float* __restrict__ Vw,
    const float* __restrict__ bv,
    float* __restrict__ ctx_out, float* __restrict__ w_out)
{
    __shared__ _Float16 lS[2][4][64][8];  // 2 slots x [mt][lane'][8] = 8 KB
    __shared__ float phl[512];
    __shared__ float Vl[512];
    __shared__ float scp[8][64];
    __shared__ float wsm[64];
    __shared__ float ctxp[2][256];

    const int tid = threadIdx.x;
    const int w = tid >> 6;
    const int l = tid & 63;
    const size_t b = blockIdx.x;
    const float* fb = feat + b * (LDIM * EDIM);

    // staging role of this thread: row r, 4-col quad q of each 32-col slab
    const int r  = tid >> 3, q = tid & 7;
    const int mt_s = r >> 4;
    const int fl   = (q >> 1) * 16 + (r & 15);  // fragment lane' (pre-XOR)
    const int h4   = (q & 1) * 4;               // half offset within half8

    // prologue: stage slab 0 + phl/Vl
    {
        float4 g = *(const float4*)(fb + r * EDIM + q * 4);
        phl[tid] = ph[b * UDIM + tid];
        Vl[tid]  = Vw[tid];
        *(half4*)&lS[0][mt_s][fl ^ 0][h4] = cvt4(g);
    }
    __syncthreads();

    floatx4 acc[4][4];  // [nt][mt]
#pragma unroll
    for (int i = 0; i < 4; ++i)
#pragma unroll
        for (int j = 0; j < 4; ++j) acc[i][j] = (floatx4){0.f, 0.f, 0.f, 0.f};

    for (int kc = 0; kc < 8; ++kc) {
        // issue next slab's 16B load first (HBM latency covered by Bc+MFMA)
        float4 g;
        if (kc < 7)
            g = *(const float4*)(fb + r * EDIM + (kc + 1) * 32 + q * 4);

        half8 Bc[4];
#pragma unroll
        for (int nt = 0; nt < 4; ++nt) Bc[nt] = *bfrag(F1, kc, w * 4 + nt, l);
#pragma unroll
        for (int mt = 0; mt < 4; ++mt) {
            const half8 a = *(const half8*)&lS[kc & 1][mt][l ^ kc][0];
#pragma unroll
            for (int nt = 0; nt < 4; ++nt)
                acc[nt][mt] = __builtin_amdgcn_mfma_f32_16x16x32_f16(
                    a, Bc[nt], acc[nt][mt], 0, 0, 0);
        }

        if (kc < 7) {
            // land slab kc+1 into the other slot; barrier publishes it
            *(half4*)&lS[(kc + 1) & 1][mt_s][fl ^ (kc + 1)][h4] = cvt4(g);
            __syncthreads();
        }
    }

    // ---- epilogue: tanh(acc + ph) * V -> per-row score partials ----
    float sv[4][4];
#pragma unroll
    for (int mt = 0; mt < 4; ++mt)
#pragma unroll
        for (int rr = 0; rr < 4; ++rr) sv[mt][rr] = 0.f;
#pragma unroll
    for (int nt = 0; nt < 4; ++nt) {
        const int n = (w * 4 + nt) * 16 + (l & 15);
        const float phn = phl[n];
        const float vn  = Vl[n];
#pragma unroll
        for (int mt = 0; mt < 4; ++mt)
#pragma unroll
            for (int rr = 0; rr < 4; ++rr)
                sv[mt][rr] += tanh_fast(acc[nt][mt][rr] + phn) * vn;
    }
#pragma unroll
    for (int mt = 0; mt < 4; ++mt)
#pragma unroll
        for (int rr = 0; rr < 4; ++rr) {
            float v = sv[mt][rr];
            v += __shfl_xor(v, 1);
            v += __shfl_xor(v, 2);
            v += __shfl_xor(v, 4);
            v += __shfl_xor(v, 8);
            if ((l & 15) == 0) scp[w][mt * 16 + (l >> 4) * 4 + rr] = v;
        }
    __syncthreads();

    // ---- softmax over L=64 (first 64 threads) ----
    if (tid < 64) {
        float s = bv[0];
#pragma unroll
        for (int wv = 0; wv < 8; ++wv) s += scp[wv][tid];
        float m = s;
        m = fmaxf(m, __shfl_xor(m, 32));
        m = fmaxf(m, __shfl_xor(m, 16));
        m = fmaxf(m, __shfl_xor(m, 8));
        m = fmaxf(m, __shfl_xor(m, 4));
        m = fmaxf(m, __shfl_xor(m, 2));
        m = fmaxf(m, __shfl_xor(m, 1));
        float e = __builtin_amdgcn_exp2f((s - m) * 1.44269504088896341f);
        float sum = e;
        sum += __shfl_xor(sum, 32);
        sum += __shfl_xor(sum, 16);
        sum += __shfl_xor(sum, 8);
        sum += __shfl_xor(sum, 4);
        sum += __shfl_xor(sum, 2);
        sum += __shfl_xor(sum, 1);
        float wgt = e / sum;
        wsm[tid] = wgt;
        w_out[b * LDIM + tid] = wgt;
    }
    __syncthreads();

    // ---- context: halves of rows per thread-group (fb is L2-hot) ----
    {
        const int e = tid & 255, h = tid >> 8;
        float c = 0.f;
#pragma unroll 8
        for (int ll = h * 32; ll < h * 32 + 32; ++ll)
            c = fmaf(wsm[ll], fb[ll * EDIM + e], c);
        ctxp[h][e] = c;
    }
    __syncthreads();
    if (tid < 256)
        ctx_out[b * EDIM + tid] = ctxp[0][tid] + ctxp[1][tid];
}

extern "C" void kernel_launch(void* const* d_in, const int* in_sizes, int n_in,
                              void* d_out, int out_size, void* d_ws, size_t ws_size,
                              hipStream_t stream) {
    const float* features = (const float*)d_in[0];
    const float* hidden   = (const float*)d_in[1];
    const float* W1       = (const float*)d_in[2];
    const float* b1       = (const float*)d_in[3];
    const float* W2       = (const float*)d_in[4];
    const float* b2       = (const float*)d_in[5];
    const float* Vw       = (const float*)d_in[6];
    const float* bv       = (const float*)d_in[7];

    float* ctx_out = (float*)d_out;
    float* w_out   = (float*)d_out + (size_t)BATCH * EDIM;

    float* ph = (float*)d_ws;
    unsigned short* F1 = (unsigned short*)(ph + (size_t)BATCH * UDIM);

    prep_all<<<dim3(144), dim3(512), 0, stream>>>(W1, W2, hidden, b1, b2, F1, ph);
    attn_main<<<dim3(BATCH), dim3(512), 0, stream>>>(
        features, F1, ph, Vw, bv, ctx_out, w_out);
}

// Round 11
// 267.295 us; speedup vs baseline: 1.0194x; 1.0194x over previous
//
#include <hip/hip_runtime.h>
#include <math.h>

#define BATCH 2048
#define LDIM 64
#define EDIM 256
#define UDIM 512

typedef __attribute__((ext_vector_type(8))) _Float16 half8;
typedef __attribute__((ext_vector_type(4))) _Float16 half4;
typedef __attribute__((ext_vector_type(4))) float floatx4;

__device__ inline float tanh_fast(float x) {
    float t = __builtin_amdgcn_exp2f(x * 2.88539008177792681f);
    return 1.f - 2.f * __builtin_amdgcn_rcpf(t + 1.f);
}
__device__ inline half8 cvt8(float4 f0, float4 f1) {
    half8 h;
    h[0] = (_Float16)f0.x; h[1] = (_Float16)f0.y;
    h[2] = (_Float16)f0.z; h[3] = (_Float16)f0.w;
    h[4] = (_Float16)f1.x; h[5] = (_Float16)f1.y;
    h[6] = (_Float16)f1.z; h[7] = (_Float16)f1.w;
    return h;
}
__device__ inline half4 cvt4(float4 f) {
    half4 h;
    h[0] = (_Float16)f.x; h[1] = (_Float16)f.y;
    h[2] = (_Float16)f.z; h[3] = (_Float16)f.w;
    return h;
}
// B-fragment pointer: layout [kc][ntg(32)][lane(64)][8 fp16]
__device__ inline const half8* bfrag(const unsigned short* F, int kc, int ntg, int l) {
    return (const half8*)(F + ((((size_t)kc * 32 + ntg) * 64 + l) << 3));
}

// ---- prep: W[K][512] fp32 -> fp16 B-fragments via coalesced LDS slab. ----
__global__ __launch_bounds__(256) void prep_frag(const float* __restrict__ W1,
                                                 const float* __restrict__ W2,
                                                 unsigned short* __restrict__ F1,
                                                 unsigned short* __restrict__ F2) {
    __shared__ float S[32 * 128];
    int bid = blockIdx.x;
    const float* W; unsigned short* F; int kc, grp;
    if (bid < 32) { W = W1; F = F1; kc = bid >> 2; grp = bid & 3; }
    else { bid -= 32; W = W2; F = F2; kc = bid >> 2; grp = bid & 3; }
    const int tid = threadIdx.x;
    const float* src = W + (size_t)kc * 32 * UDIM + grp * 128;
    float4* Sv = (float4*)S;
#pragma unroll
    for (int i = 0; i < 4; ++i) {
        int f = tid + i * 256;
        int k = f >> 5, c4 = f & 31;
        Sv[f] = *(const float4*)(src + (size_t)k * UDIM + c4 * 4);
    }
    __syncthreads();
#pragma unroll
    for (int i = 0; i < 2; ++i) {
        int u = tid + i * 256;
        int lane = u & 63, ntl = u >> 6;
        int n_loc = ntl * 16 + (lane & 15);
        int k0 = (lane >> 4) * 8;
        half8 h;
#pragma unroll
        for (int j = 0; j < 8; ++j)
            h[j] = (_Float16)S[(k0 + j) * 128 + n_loc];
        int ntg = grp * 8 + ntl;
        *(half8*)(F + (((size_t)kc * 32 + ntg) * 64 + lane) * 8) = h;
    }
}

// ---- prep_ph: ph = hidden @ W2 + b1 + b2.  M=8/block, 256 blocks x 512 thr:
// every CU gets one 8-wave block, each wave owns 64 cols (4 ntg) -> 1/4 the
// per-wave serial depth of the old 128x256 version.  A-rows for lanes 8..15
// duplicate rows 0..7 (clamped); garbage C rows 8..15 are store-masked.
// Bit-identical ph values (same kc order, same fragment math).
__global__ __launch_bounds__(512) void prep_ph(const float* __restrict__ hidden,
                                               const unsigned short* __restrict__ F2,
                                               const float* __restrict__ b1,
                                               const float* __restrict__ b2,
                                               float* __restrict__ ph) {
    const int tid = threadIdx.x;
    const int w = tid >> 6;
    const int l = tid & 63;
    const int r0 = blockIdx.x * 8;

    floatx4 acc[4];
#pragma unroll
    for (int i = 0; i < 4; ++i) acc[i] = (floatx4){0.f, 0.f, 0.f, 0.f};

    // clamp A row: lanes with (l&15)>=8 duplicate rows 0..7 (masked at store)
    const float* ap = hidden + (size_t)(r0 + (l & 7)) * UDIM + ((l >> 4) << 3);

    float4 a0 = *(const float4*)(ap);
    float4 a1 = *(const float4*)(ap + 4);
    half8 B[4];
#pragma unroll
    for (int nt = 0; nt < 4; ++nt) B[nt] = *bfrag(F2, 0, w * 4 + nt, l);

    for (int kc = 0; kc < 16; ++kc) {
        half8 a = cvt8(a0, a1);
        float4 n0, n1; half8 NB[4];
        if (kc < 15) {
            n0 = *(const float4*)(ap + (kc + 1) * 32);
            n1 = *(const float4*)(ap + (kc + 1) * 32 + 4);
#pragma unroll
            for (int nt = 0; nt < 4; ++nt) NB[nt] = *bfrag(F2, kc + 1, w * 4 + nt, l);
        }
#pragma unroll
        for (int nt = 0; nt < 4; ++nt)
            acc[nt] = __builtin_amdgcn_mfma_f32_16x16x32_f16(a, B[nt], acc[nt], 0, 0, 0);
        if (kc < 15) {
            a0 = n0; a1 = n1;
#pragma unroll
            for (int nt = 0; nt < 4; ++nt) B[nt] = NB[nt];
        }
    }
#pragma unroll
    for (int nt = 0; nt < 4; ++nt) {
        const int n = (w * 4 + nt) * 16 + (l & 15);
        const float bias = b1[n] + b2[n];
#pragma unroll
        for (int r = 0; r < 4; ++r) {
            const int m = (l >> 4) * 4 + r;
            if (m < 8)
                ph[(size_t)(r0 + m) * UDIM + n] = acc[nt][r] + bias;
        }
    }
}

// ---- main: round-8 pipelined-slab version + T5 setprio around MFMA cluster.
__global__ __launch_bounds__(512, 4) void attn_main(
    const float* __restrict__ feat, const unsigned short* __restrict__ F1,
    const float* __restrict__ ph, const float* __restrict__ Vw,
    const float* __restrict__ bv,
    float* __restrict__ ctx_out, float* __restrict__ w_out)
{
    __shared__ _Float16 lS[2][4][64][8];  // 2 slots x [mt][lane'][8] = 8 KB
    __shared__ float phl[512];
    __shared__ float Vl[512];
    __shared__ float scp[8][64];
    __shared__ float wsm[64];
    __shared__ float ctxp[2][256];

    const int tid = threadIdx.x;
    const int w = tid >> 6;
    const int l = tid & 63;
    const size_t b = blockIdx.x;
    const float* fb = feat + b * (LDIM * EDIM);

    // staging role of this thread: row r, 4-col quad q of each 32-col slab
    const int r  = tid >> 3, q = tid & 7;
    const int mt_s = r >> 4;
    const int fl   = (q >> 1) * 16 + (r & 15);  // fragment lane' (pre-XOR)
    const int h4   = (q & 1) * 4;               // half offset within half8

    // prologue: stage slab 0 + phl/Vl
    {
        float4 g = *(const float4*)(fb + r * EDIM + q * 4);
        phl[tid] = ph[b * UDIM + tid];
        Vl[tid]  = Vw[tid];
        *(half4*)&lS[0][mt_s][fl ^ 0][h4] = cvt4(g);
    }
    __syncthreads();

    floatx4 acc[4][4];  // [nt][mt]
#pragma unroll
    for (int i = 0; i < 4; ++i)
#pragma unroll
        for (int j = 0; j < 4; ++j) acc[i][j] = (floatx4){0.f, 0.f, 0.f, 0.f};

    for (int kc = 0; kc < 8; ++kc) {
        // issue next slab's 16B load first (HBM latency covered by Bc+MFMA)
        float4 g;
        if (kc < 7)
            g = *(const float4*)(fb + r * EDIM + (kc + 1) * 32 + q * 4);

        half8 Bc[4];
#pragma unroll
        for (int nt = 0; nt < 4; ++nt) Bc[nt] = *bfrag(F1, kc, w * 4 + nt, l);

        __builtin_amdgcn_s_setprio(1);
#pragma unroll
        for (int mt = 0; mt < 4; ++mt) {
            const half8 a = *(const half8*)&lS[kc & 1][mt][l ^ kc][0];
#pragma unroll
            for (int nt = 0; nt < 4; ++nt)
                acc[nt][mt] = __builtin_amdgcn_mfma_f32_16x16x32_f16(
                    a, Bc[nt], acc[nt][mt], 0, 0, 0);
        }
        __builtin_amdgcn_s_setprio(0);

        if (kc < 7) {
            // land slab kc+1 into the other slot; barrier publishes it
            *(half4*)&lS[(kc + 1) & 1][mt_s][fl ^ (kc + 1)][h4] = cvt4(g);
            __syncthreads();
        }
    }

    // ---- epilogue: tanh(acc + ph) * V -> per-row score partials ----
    float sv[4][4];
#pragma unroll
    for (int mt = 0; mt < 4; ++mt)
#pragma unroll
        for (int rr = 0; rr < 4; ++rr) sv[mt][rr] = 0.f;
#pragma unroll
    for (int nt = 0; nt < 4; ++nt) {
        const int n = (w * 4 + nt) * 16 + (l & 15);
        const float phn = phl[n];
        const float vn  = Vl[n];
#pragma unroll
        for (int mt = 0; mt < 4; ++mt)
#pragma unroll
            for (int rr = 0; rr < 4; ++rr)
                sv[mt][rr] += tanh_fast(acc[nt][mt][rr] + phn) * vn;
    }
#pragma unroll
    for (int mt = 0; mt < 4; ++mt)
#pragma unroll
        for (int rr = 0; rr < 4; ++rr) {
            float v = sv[mt][rr];
            v += __shfl_xor(v, 1);
            v += __shfl_xor(v, 2);
            v += __shfl_xor(v, 4);
            v += __shfl_xor(v, 8);
            if ((l & 15) == 0) scp[w][mt * 16 + (l >> 4) * 4 + rr] = v;
        }
    __syncthreads();

    // ---- softmax over L=64 (first 64 threads) ----
    if (tid < 64) {
        float s = bv[0];
#pragma unroll
        for (int wv = 0; wv < 8; ++wv) s += scp[wv][tid];
        float m = s;
        m = fmaxf(m, __shfl_xor(m, 32));
        m = fmaxf(m, __shfl_xor(m, 16));
        m = fmaxf(m, __shfl_xor(m, 8));
        m = fmaxf(m, __shfl_xor(m, 4));
        m = fmaxf(m, __shfl_xor(m, 2));
        m = fmaxf(m, __shfl_xor(m, 1));
        float e = __builtin_amdgcn_exp2f((s - m) * 1.44269504088896341f);
        float sum = e;
        sum += __shfl_xor(sum, 32);
        sum += __shfl_xor(sum, 16);
        sum += __shfl_xor(sum, 8);
        sum += __shfl_xor(sum, 4);
        sum += __shfl_xor(sum, 2);
        sum += __shfl_xor(sum, 1);
        float wgt = e / sum;
        wsm[tid] = wgt;
        w_out[b * LDIM + tid] = wgt;
    }
    __syncthreads();

    // ---- context: halves of rows per thread-group (fb is L2-hot) ----
    {
        const int e = tid & 255, h = tid >> 8;
        float c = 0.f;
#pragma unroll 8
        for (int ll = h * 32; ll < h * 32 + 32; ++ll)
            c = fmaf(wsm[ll], fb[ll * EDIM + e], c);
        ctxp[h][e] = c;
    }
    __syncthreads();
    if (tid < 256)
        ctx_out[b * EDIM + tid] = ctxp[0][tid] + ctxp[1][tid];
}

extern "C" void kernel_launch(void* const* d_in, const int* in_sizes, int n_in,
                              void* d_out, int out_size, void* d_ws, size_t ws_size,
                              hipStream_t stream) {
    const float* features = (const float*)d_in[0];
    const float* hidden   = (const float*)d_in[1];
    const float* W1       = (const float*)d_in[2];
    const float* b1       = (const float*)d_in[3];
    const float* W2       = (const float*)d_in[4];
    const float* b2       = (const float*)d_in[5];
    const float* Vw       = (const float*)d_in[6];
    const float* bv       = (const float*)d_in[7];

    float* ctx_out = (float*)d_out;
    float* w_out   = (float*)d_out + (size_t)BATCH * EDIM;

    float* ph = (float*)d_ws;
    unsigned short* F1 = (unsigned short*)(ph + (size_t)BATCH * UDIM);
    unsigned short* F2 = F1 + (size_t)8 * 32 * 64 * 8;

    prep_frag<<<dim3(96), dim3(256), 0, stream>>>(W1, W2, F1, F2);
    prep_ph<<<dim3(256), dim3(512), 0, stream>>>(hidden, F2, b1, b2, ph);
    attn_main<<<dim3(BATCH), dim3(512), 0, stream>>>(
        features, F1, ph, Vw, bv, ctx_out, w_out);
}